// Round 6
// baseline (71.498 us; speedup 1.0000x reference)
//
#include <hip/hip_runtime.h>
#include <math.h>

#define B 64
#define N 16384
#define K 16
#define NCHUNK 16      // chunks per row (1024 elements each)
// ws layout (floats):
//   wsV  [B][NCHUNK][K]  candidate values   : 16384 floats @ 0
//   wsI  [B][NCHUNK][K]  candidate indices  : 16384 ints   @ 16384
//   wsS  [B][NCHUNK]     chunk exp sums     : 1024 floats  @ 32768
//   wsM  [B][NCHUNK]     chunk max          : 1024 floats  @ 33792
//   wsC  [B][48]         row constants      : c[0..15], idx[16..31](int), m0 @ [32]

#define WSI_OFF 16384
#define WSS_OFF 32768
#define WSM_OFF 33792
#define WSC_OFF 34816

typedef float f4 __attribute__((ext_vector_type(4)));

__device__ __forceinline__ void wave_argmax(float& vmax, int& imax) {
#pragma unroll
  for (int off = 32; off; off >>= 1) {
    const float ov = __shfl_down(vmax, off);
    const int   oi = __shfl_down(imax, off);
    if (ov > vmax || (ov == vmax && oi < imax)) { vmax = ov; imax = oi; }
  }
  vmax = __shfl(vmax, 0);
  imax = __shfl(imax, 0);
}

__device__ __forceinline__ float wave_sum(float v) {
#pragma unroll
  for (int off = 32; off; off >>= 1) v += __shfl_down(v, off);
  return v;
}

// ---------------- Kernel A: per-chunk top-16 candidates + exp partial sums ----------------
// 1024 blocks x 256 threads; block = (row b, chunk c) of 1024 contiguous elements.
__global__ __launch_bounds__(256)
void gtk_partial(const float* __restrict__ logits, const float* __restrict__ gumbel,
                 float* __restrict__ ws) {
  const int blk  = blockIdx.x;
  const int tid  = threadIdx.x;
  const int wave = tid >> 6, lane = tid & 63;
  const int b = blk >> 4, c = blk & 15;
  const size_t gbase = (size_t)blk << 10;

  const f4 lv = *(const f4*)(logits + gbase + (tid << 2));
  const f4 gv = *(const f4*)(gumbel + gbase + (tid << 2));
  float x[4];
#pragma unroll
  for (int e = 0; e < 4; ++e) x[e] = lv[e] + gv[e];
  const int myn = (c << 10) + (tid << 2);   // row-local index of x[0]

  __shared__ float sv[64];
  __shared__ int   si[64];
  __shared__ float spart[5];
  __shared__ float smc;

  // wave-local sequential top-16 over 256 elements (no barriers)
#pragma unroll 1
  for (int k = 0; k < K; ++k) {
    float vmax = -INFINITY; int imax = 0x7fffffff;
#pragma unroll
    for (int e = 0; e < 4; ++e)
      if (x[e] > vmax) { vmax = x[e]; imax = myn + e; }   // ascending e: first wins ties
    wave_argmax(vmax, imax);
    if (lane == 0) { sv[wave * K + k] = vmax; si[wave * K + k] = imax; }
#pragma unroll
    for (int e = 0; e < 4; ++e)
      if (myn + e == imax) x[e] = -INFINITY;
  }
  __syncthreads();

  // wave 0: merge 64 wave-candidates -> chunk top-16, write to ws
  if (wave == 0) {
    float cv = sv[lane]; int ci = si[lane];
    float mc = 0.f;
    float* wV = ws + ((size_t)b * NCHUNK + c) * K;
    int*   wI = (int*)(ws + WSI_OFF) + ((size_t)b * NCHUNK + c) * K;
#pragma unroll 1
    for (int k = 0; k < K; ++k) {
      float vmax = cv; int imax = ci;
      wave_argmax(vmax, imax);
      if (k == 0) { mc = vmax; if (lane == 0) smc = vmax; }
      if (lane == 0) { wV[k] = vmax; wI[k] = imax; }
      if (ci == imax) cv = -INFINITY;
    }
    // leftover: the 48 unselected wave-candidates go back into the chunk sum
    float ls = wave_sum(__expf((cv - mc) * 1.5f));
    if (lane == 0) spart[4] = ls;
  }
  __syncthreads();

  const float mc = smc;
  float p = 0.f;
#pragma unroll
  for (int e = 0; e < 4; ++e) p += __expf((x[e] - mc) * 1.5f);  // masked -> exp(-inf)=0
  p = wave_sum(p);
  if (lane == 0) spart[wave] = p;
  __syncthreads();

  if (tid == 0) {
    const float S = spart[0] + spart[1] + spart[2] + spart[3] + spart[4];
    (ws + WSS_OFF)[b * NCHUNK + c] = S;
    (ws + WSM_OFF)[b * NCHUNK + c] = mc;
  }
}

// ---------------- Kernel M: one wave per row merges 256 candidates -> constants ----------------
// 64 blocks x 64 threads. FULLY UNROLLED merge: ev[]/ei[] stay in registers.
__global__ __launch_bounds__(64)
void gtk_merge(float* __restrict__ ws) {
  const int b    = blockIdx.x;
  const int lane = threadIdx.x;

  const float* wV = ws + (size_t)b * (NCHUNK * K);
  const int*   wI = (const int*)(ws + WSI_OFF) + (size_t)b * (NCHUNK * K);

  float cv[4]; int ci[4];
#pragma unroll
  for (int r = 0; r < 4; ++r) { cv[r] = wV[lane + 64 * r]; ci[r] = wI[lane + 64 * r]; }

  float ev[K]; int ei[K];
#pragma unroll
  for (int k = 0; k < K; ++k) {       // full unroll: ev[k]/ei[k] static
    float vmax = -INFINITY; int imax = 0x7fffffff;
#pragma unroll
    for (int r = 0; r < 4; ++r)
      if (cv[r] > vmax || (cv[r] == vmax && ci[r] < imax)) { vmax = cv[r]; imax = ci[r]; }
    wave_argmax(vmax, imax);
    ev[k] = vmax; ei[k] = imax;
#pragma unroll
    for (int r = 0; r < 4; ++r)
      if (ci[r] == imax) cv[r] = -INFINITY;
  }

  const float m0 = ev[0];
  // A' = unselected candidates (add-back) + rescaled chunk sums
  float acc = 0.f;
#pragma unroll
  for (int r = 0; r < 4; ++r) acc += __expf((cv[r] - m0) * 1.5f);
  if (lane < NCHUNK) {
    const float S  = (ws + WSS_OFF)[b * NCHUNK + lane];
    const float mc = (ws + WSM_OFF)[b * NCHUNK + lane];
    acc += S * __expf((mc - m0) * 1.5f);
  }
  const float A = wave_sum(acc);

  if (lane == 0) {
    float* wrow = ws + WSC_OFF + (size_t)b * 48;
    float T = 0.f;
    float c[K];
#pragma unroll
    for (int j = K - 1; j >= 0; --j) { T += __expf((ev[j] - m0) * 1.5f); c[j] = 1.0f / (A + T); }
#pragma unroll
    for (int j = 0; j < K; ++j) wrow[j] = c[j];
    int* wi = (int*)(wrow + K);
#pragma unroll
    for (int j = 0; j < K; ++j) wi[j] = ei[j];
    wrow[32] = m0;
  }
}

// ---------------- Kernel W: plane-contiguous writes ----------------
// 8192 blocks x 256 threads. Block = (plane-slot p, segment seg).
//   p in [0,16): st plane k=p (one-hot; NO input reads)
//   p in [16,32): softs plane k=p-16 (reads logits/gumbel segment, L2-hot)
// Each block writes one CONTIGUOUS 4096-elem (16 KB) run of a single plane.
// XCD swizzle: bid%8 = XCD; within an XCD, the 32 plane-slots of one segment run
// back-to-back so the input segment is read once from HBM, 15x from L2.
__global__ __launch_bounds__(256)
void gtk_write(const float* __restrict__ logits, const float* __restrict__ gumbel,
               const float* __restrict__ ws, float* __restrict__ st,
               float* __restrict__ softs) {
  const int bid = blockIdx.x;
  const int tid = threadIdx.x;
  const int xcd  = bid & 7;
  const int jj   = bid >> 3;
  const int p    = jj & 31;            // plane-slot
  const int segl = jj >> 5;            // 0..31
  const int seg  = (segl << 3) | xcd;  // 0..255  (row b, quarter q)
  const int b    = seg >> 2;
  const int n0   = (seg & 3) << 12;    // 4096-element segment base within row
  const int k    = p & 15;

  __shared__ int   sidx[K];
  __shared__ float sck;
  __shared__ float sm0;

  const float* wrow = ws + WSC_OFF + (size_t)b * 48;
  if (tid < K) sidx[tid] = ((const int*)(wrow + K))[tid];
  if (tid == 0) { sck = wrow[k]; sm0 = wrow[32]; }
  __syncthreads();

  const size_t plane = (size_t)B * N;
  const size_t base  = ((size_t)b << 14) + n0;   // into [B*N]

  if (p < 16) {
    // ---- st plane k: stream zeros, single 1 at sidx[k] if it lands here ----
    float* dst = st + (size_t)k * plane + base;
    const int sel = sidx[k] - n0;                // ours if in [0,4096)
#pragma unroll
    for (int i = 0; i < 4; ++i) {
      const int off = i * 1024 + (tid << 2);     // [0,4096) coverage, 1024/iter
      f4 h = {0.f, 0.f, 0.f, 0.f};
      const int d = sel - off;
      if ((unsigned)d < 4u) h[d] = 1.f;
      __builtin_nontemporal_store(h, (f4*)(dst + off));
    }
  } else {
    // ---- softs plane k: E*c_k, zero at positions selected before step k ----
    const float ck = sck;
    const float m0 = sm0;
    const float* lg = logits + base;
    const float* gm = gumbel + base;
    float* dst = softs + (size_t)k * plane + base;
#pragma unroll
    for (int i = 0; i < 4; ++i) {
      const int off = i * 1024 + (tid << 2);     // [0,4096) coverage, 1024/iter
      const f4 lv = *(const f4*)(lg + off);
      const f4 gv = *(const f4*)(gm + off);
      int zmask = 0;                             // bit e: element e selected before k
#pragma unroll
      for (int j = 0; j < K; ++j) {
        const int d = sidx[j] - (n0 + off);
        if ((j < k) & ((unsigned)d < 4u)) zmask |= (1 << d);
      }
      f4 s;
#pragma unroll
      for (int e = 0; e < 4; ++e)
        s[e] = ((zmask >> e) & 1) ? 0.f : __expf((lv[e] + gv[e] - m0) * 1.5f) * ck;
      __builtin_nontemporal_store(s, (f4*)(dst + off));
    }
  }
}

extern "C" void kernel_launch(void* const* d_in, const int* in_sizes, int n_in,
                              void* d_out, int out_size, void* d_ws, size_t ws_size,
                              hipStream_t stream) {
  const float* logits = (const float*)d_in[0];
  const float* gumbel = (const float*)d_in[1];
  float* st    = (float*)d_out;                      // [K,B,N]
  float* softs = st + (size_t)K * B * N;             // [K,B,N]
  float* ws    = (float*)d_ws;

  gtk_partial<<<B * NCHUNK, 256, 0, stream>>>(logits, gumbel, ws);
  gtk_merge<<<B, 64, 0, stream>>>(ws);
  gtk_write<<<32 * 256, 256, 0, stream>>>(logits, gumbel, ws, st, softs);
}

// Round 7
// 58.563 us; speedup vs baseline: 1.2209x; 1.2209x over previous
//
#include <hip/hip_runtime.h>
#include <math.h>

#define B 64
#define N 16384
#define K 16
#define CHUNK 256                 // elements per wave-chunk
#define NCH   (N / CHUNK)         // 64 chunks per row
// ws float layout:
//   wV [B][NCH][K]  candidate values  @ 0       (65536 floats)
//   wI [B][NCH][K]  candidate indices @ 65536   (65536 ints)
//   wS [B][NCH]     chunk exp sums    @ 131072  (4096)
//   wM [B][NCH]     chunk max         @ 135168  (4096)
//   wC [B][48]      row consts        @ 139264  (c[16], idx[16] int, m0@32)
#define WV_OFF 0
#define WI_OFF 65536
#define WS_OFF 131072
#define WM_OFF 135168
#define WC_OFF 139264

typedef float f4 __attribute__((ext_vector_type(4)));

// monotone map fp32 -> uint32 (no NaNs in data)
__device__ __forceinline__ unsigned ordu(float x) {
  unsigned i = __float_as_uint(x);
  return (i & 0x80000000u) ? ~i : (i | 0x80000000u);
}
__device__ __forceinline__ int mbcnt64(unsigned long long m) {
  return __builtin_amdgcn_mbcnt_hi((unsigned)(m >> 32),
         __builtin_amdgcn_mbcnt_lo((unsigned)m, 0u));
}

// ---------------- Kernel P: per-chunk (256 elems / wave) top-16 + full exp sum ----------------
// 1024 blocks x 256 threads = 4096 waves; wave = one chunk; ZERO barriers.
__global__ __launch_bounds__(256)
void gtk_partial(const float* __restrict__ logits, const float* __restrict__ gumbel,
                 float* __restrict__ ws) {
  const int tid  = threadIdx.x;
  const int wave = tid >> 6, lane = tid & 63;
  const int gch  = blockIdx.x * 4 + wave;        // global chunk id (b*NCH + c)
  const int c    = gch & (NCH - 1);
  const size_t base = (size_t)gch * CHUNK;

  // slot-major layout: element e of lane = base + e*64 + lane  (slot order == index order)
  float x[4]; unsigned u[4];
#pragma unroll
  for (int e = 0; e < 4; ++e) {
    const int o = e * 64 + lane;
    x[e] = logits[base + o] + gumbel[base + o];
    u[e] = ordu(x[e]);
  }

  // chunk max (butterfly, values only)
  float mc = fmaxf(fmaxf(x[0], x[1]), fmaxf(x[2], x[3]));
#pragma unroll
  for (int off = 32; off; off >>= 1) mc = fmaxf(mc, __shfl_xor(mc, off));

  // chunk exp sum over ALL elements (selection does not mask; merge subtracts)
  float s = 0.f;
#pragma unroll
  for (int e = 0; e < 4; ++e) s += __expf((x[e] - mc) * 1.5f);
#pragma unroll
  for (int off = 32; off; off >>= 1) s += __shfl_xor(s, off);

  // radix bit-search: p = 16th largest orderable value in chunk
  unsigned p = 0;
#pragma unroll
  for (int bit = 31; bit >= 0; --bit) {
    const unsigned test = p | (1u << bit);
    int cnt = 0;
#pragma unroll
    for (int e = 0; e < 4; ++e) cnt += __popcll(__ballot(u[e] >= test));
    if (cnt >= K) p = test;
  }

  // extract top-16 set via ballot-prefix ranks (unsorted; merge re-orders)
  unsigned long long bgt[4], beq[4];
#pragma unroll
  for (int e = 0; e < 4; ++e) { bgt[e] = __ballot(u[e] > p); beq[e] = __ballot(u[e] == p); }
  const int tg = __popcll(bgt[0]) + __popcll(bgt[1]) + __popcll(bgt[2]) + __popcll(bgt[3]);
  const int need = K - tg;                        // ties taken smallest-index-first
  float* wV = ws + WV_OFF + (size_t)gch * K;
  int*   wI = (int*)(ws + WI_OFF) + (size_t)gch * K;
  int gpre = 0, epre = 0;
#pragma unroll
  for (int e = 0; e < 4; ++e) {
    const int myi = (c << 8) + e * 64 + lane;     // row-local index
    if (u[e] > p) {
      const int r = gpre + mbcnt64(bgt[e]);
      wV[r] = x[e]; wI[r] = myi;
    } else if (u[e] == p) {
      const int r = epre + mbcnt64(beq[e]);
      if (r < need) { wV[tg + r] = x[e]; wI[tg + r] = myi; }
    }
    gpre += __popcll(bgt[e]); epre += __popcll(beq[e]);
  }

  if (lane == 0) {
    (ws + WS_OFF)[gch] = s;
    (ws + WM_OFF)[gch] = mc;
  }
}

// ---------------- Kernel M: per-row merge of 1024 candidates -> constants ----------------
// 64 blocks x 256 threads. Wave-level radix-select (256 cands/wave) -> 64 survivors
// -> wave-0 radix-select -> exact rank-sort of final 16 -> c_k, idx, m0.
__global__ __launch_bounds__(256)
void gtk_merge(float* __restrict__ ws) {
  const int b = blockIdx.x;
  const int tid = threadIdx.x, wave = tid >> 6, lane = tid & 63;

  __shared__ float lv[64];
  __shared__ int   li[64];
  __shared__ float tv[K];
  __shared__ int   ti[K];
  __shared__ float sv16[K];
  __shared__ int   si16[K];

  const float* wV = ws + WV_OFF + (size_t)b * (NCH * K);
  const int*   wI = (const int*)(ws + WI_OFF) + (size_t)b * (NCH * K);

  float xv[4]; unsigned xu[4]; int xi[4];
#pragma unroll
  for (int e = 0; e < 4; ++e) {
    const int q = wave * 256 + e * 64 + lane;
    xv[e] = wV[q]; xi[e] = wI[q]; xu[e] = ordu(xv[e]);
  }

  unsigned p = 0;
#pragma unroll
  for (int bit = 31; bit >= 0; --bit) {
    const unsigned test = p | (1u << bit);
    int cnt = 0;
#pragma unroll
    for (int e = 0; e < 4; ++e) cnt += __popcll(__ballot(xu[e] >= test));
    if (cnt >= K) p = test;
  }
  unsigned long long bgt[4], beq[4];
#pragma unroll
  for (int e = 0; e < 4; ++e) { bgt[e] = __ballot(xu[e] > p); beq[e] = __ballot(xu[e] == p); }
  const int tg = __popcll(bgt[0]) + __popcll(bgt[1]) + __popcll(bgt[2]) + __popcll(bgt[3]);
  const int need = K - tg;
  int gpre = 0, epre = 0;
#pragma unroll
  for (int e = 0; e < 4; ++e) {
    if (xu[e] > p) {
      const int r = gpre + mbcnt64(bgt[e]);
      lv[wave * K + r] = xv[e]; li[wave * K + r] = xi[e];
    } else if (xu[e] == p) {
      const int r = epre + mbcnt64(beq[e]);
      if (r < need) { lv[wave * K + tg + r] = xv[e]; li[wave * K + tg + r] = xi[e]; }
    }
    gpre += __popcll(bgt[e]); epre += __popcll(beq[e]);
  }
  __syncthreads();

  if (wave == 0) {
    const float v = lv[lane]; const int i = li[lane];
    const unsigned uu = ordu(v);
    unsigned p2 = 0;
#pragma unroll
    for (int bit = 31; bit >= 0; --bit) {
      const unsigned test = p2 | (1u << bit);
      if (__popcll(__ballot(uu >= test)) >= K) p2 = test;
    }
    const unsigned long long g = __ballot(uu > p2);
    const unsigned long long q = __ballot(uu == p2);
    const int tg2 = __popcll(g), nd2 = K - tg2;
    if (uu > p2) {
      const int r = mbcnt64(g);
      tv[r] = v; ti[r] = i;
    } else if (uu == p2) {
      const int r = mbcnt64(q);
      if (r < nd2) { tv[tg2 + r] = v; ti[tg2 + r] = i; }
    }
    // exact order: rank by (value desc, original index asc) among the 16
    if (lane < K) {
      const float mv = tv[lane]; const int mi = ti[lane];
      int rk = 0;
#pragma unroll
      for (int j = 0; j < K; ++j) {
        const float ov = tv[j]; const int oi = ti[j];
        rk += (ov > mv || (ov == mv && oi < mi)) ? 1 : 0;
      }
      sv16[rk] = mv; si16[rk] = mi;
    }
    const float m0 = sv16[0];

    // A_all = sum over all row elements of exp((x - m0)*1.5), from chunk sums
    const float S  = (ws + WS_OFF)[b * NCH + lane];   // NCH == 64 == wave width
    const float mcc = (ws + WM_OFF)[b * NCH + lane];
    float a = S * __expf((mcc - m0) * 1.5f);
#pragma unroll
    for (int off = 32; off; off >>= 1) a += __shfl_xor(a, off);

    if (lane == 0) {
      float* wrow = ws + WC_OFF + (size_t)b * 48;
      float D = a;                                  // D_k = A_all - sum_{j<k} e_j
#pragma unroll
      for (int j = 0; j < K; ++j) {
        wrow[j] = 1.0f / D;
        D -= __expf((sv16[j] - m0) * 1.5f);
      }
      int* wi = (int*)(wrow + K);
#pragma unroll
      for (int j = 0; j < K; ++j) wi[j] = si16[j];
      wrow[32] = m0;
    }
  }
}

// ---------------- Kernel W: plane writes, inputs read exactly once ----------------
// 512 blocks x 512 threads; block = 2048-elem segment of one row; 16 k-planes
// of st and softs written from registers; PLAIN float4 stores.
__global__ __launch_bounds__(512)
void gtk_write(const float* __restrict__ logits, const float* __restrict__ gumbel,
               const float* __restrict__ ws, float* __restrict__ st,
               float* __restrict__ softs) {
  const int tid = threadIdx.x;
  const size_t g0 = ((size_t)blockIdx.x << 11) + ((size_t)tid << 2);
  const int b  = (int)(g0 >> 14);
  const int n0 = (int)(g0 & (N - 1));

  __shared__ float sck[K];
  __shared__ int   sidx[K];
  __shared__ float sm0;
  const float* wrow = ws + WC_OFF + (size_t)b * 48;
  if (tid < K) { sck[tid] = wrow[tid]; sidx[tid] = ((const int*)(wrow + K))[tid]; }
  if (tid == 0) sm0 = wrow[32];

  const f4 lv = *(const f4*)(logits + g0);
  const f4 gv = *(const f4*)(gumbel + g0);
  __syncthreads();

  const float m0 = sm0;
  f4 E;
#pragma unroll
  for (int e = 0; e < 4; ++e) E[e] = __expf((lv[e] + gv[e] - m0) * 1.5f);

  // jh[e] = selection step of my element e (or K if never selected)
  int jh[4] = {K, K, K, K};
#pragma unroll
  for (int j = 0; j < K; ++j) {
    const int d = sidx[j] - n0;
    if ((unsigned)d < 4u) jh[d] = j;
  }

  const size_t plane = (size_t)B * N;
#pragma unroll
  for (int k = 0; k < K; ++k) {
    const float ck = sck[k];
    f4 s, h;
#pragma unroll
    for (int e = 0; e < 4; ++e) {
      s[e] = (jh[e] < k) ? 0.f : E[e] * ck;
      h[e] = (jh[e] == k) ? 1.f : 0.f;
    }
    *(f4*)(softs + k * plane + g0) = s;
    *(f4*)(st    + k * plane + g0) = h;
  }
}

extern "C" void kernel_launch(void* const* d_in, const int* in_sizes, int n_in,
                              void* d_out, int out_size, void* d_ws, size_t ws_size,
                              hipStream_t stream) {
  const float* logits = (const float*)d_in[0];
  const float* gumbel = (const float*)d_in[1];
  float* st    = (float*)d_out;                      // [K,B,N]
  float* softs = st + (size_t)K * B * N;             // [K,B,N]
  float* ws    = (float*)d_ws;

  gtk_partial<<<(B * NCH) / 4, 256, 0, stream>>>(logits, gumbel, ws);
  gtk_merge<<<B, 256, 0, stream>>>(ws);
  gtk_write<<<(B * N) / 2048, 512, 0, stream>>>(logits, gumbel, ws, st, softs);
}

// Round 8
// 43.255 us; speedup vs baseline: 1.6529x; 1.3539x over previous
//
#include <hip/hip_runtime.h>
#include <math.h>

#define B 64
#define N 16384
#define K 16
#define CHUNK 256                 // elements per wave-chunk
#define NCH   (N / CHUNK)         // 64 chunks per row
// ws float layout:
//   wV [B][NCH][K]  candidate values  @ 0       (65536 floats)
//   wI [B][NCH][K]  candidate indices @ 65536   (65536 ints)
//   wS [B][NCH]     chunk exp sums    @ 131072  (4096)
//   wM [B][NCH]     chunk max         @ 135168  (4096)
//   wC [B][48]      row consts        @ 139264  (c[16], idx[16] int, m0@32)
#define WV_OFF 0
#define WI_OFF 65536
#define WS_OFF 131072
#define WM_OFF 135168
#define WC_OFF 139264

typedef float f4 __attribute__((ext_vector_type(4)));

// monotone map fp32 -> uint32 (no NaNs in data)
__device__ __forceinline__ unsigned ordu(float x) {
  unsigned i = __float_as_uint(x);
  return (i & 0x80000000u) ? ~i : (i | 0x80000000u);
}
__device__ __forceinline__ int mbcnt64(unsigned long long m) {
  return __builtin_amdgcn_mbcnt_hi((unsigned)(m >> 32),
         __builtin_amdgcn_mbcnt_lo((unsigned)m, 0u));
}

// ---------------- Kernel P: per-chunk top-16 + full exp sum + st ZERO-FILL ----------------
// 1024 blocks x 256 threads; wave = one 256-elem chunk. Also zero-fills a
// contiguous 64 KB region of st per block (fillBuffer-style linear stores that
// overlap the radix latency chain).
__global__ __launch_bounds__(256)
void gtk_partial(const float* __restrict__ logits, const float* __restrict__ gumbel,
                 float* __restrict__ ws, float* __restrict__ st) {
  const int tid  = threadIdx.x;
  const int wave = tid >> 6, lane = tid & 63;
  const int gch  = blockIdx.x * 4 + wave;        // global chunk id (b*NCH + c)
  const int c    = gch & (NCH - 1);
  const size_t base = (size_t)gch * CHUNK;

  // slot-major layout: element e of lane = base + e*64 + lane (slot order == index order)
  float x[4]; unsigned u[4];
#pragma unroll
  for (int e = 0; e < 4; ++e) {
    const int o = e * 64 + lane;
    x[e] = logits[base + o] + gumbel[base + o];
    u[e] = ordu(x[e]);
  }

  // ---- st zero-fill: block owns st[blk*16384 .. +16384) ----
  {
    float* zst = st + ((size_t)blockIdx.x << 14);
    const f4 z = {0.f, 0.f, 0.f, 0.f};
#pragma unroll
    for (int i = 0; i < 16; ++i)
      *(f4*)(zst + i * 1024 + (tid << 2)) = z;
  }

  // chunk max (butterfly)
  float mc = fmaxf(fmaxf(x[0], x[1]), fmaxf(x[2], x[3]));
#pragma unroll
  for (int off = 32; off; off >>= 1) mc = fmaxf(mc, __shfl_xor(mc, off));

  // chunk exp sum over ALL elements (merge subtracts the selected 16)
  float s = 0.f;
#pragma unroll
  for (int e = 0; e < 4; ++e) s += __expf((x[e] - mc) * 1.5f);
#pragma unroll
  for (int off = 32; off; off >>= 1) s += __shfl_xor(s, off);

  // radix bit-search: p = 16th largest orderable value in chunk
  unsigned p = 0;
#pragma unroll
  for (int bit = 31; bit >= 0; --bit) {
    const unsigned test = p | (1u << bit);
    int cnt = 0;
#pragma unroll
    for (int e = 0; e < 4; ++e) cnt += __popcll(__ballot(u[e] >= test));
    if (cnt >= K) p = test;
  }

  // extract top-16 set via ballot-prefix ranks (ties: smallest index first)
  unsigned long long bgt[4], beq[4];
#pragma unroll
  for (int e = 0; e < 4; ++e) { bgt[e] = __ballot(u[e] > p); beq[e] = __ballot(u[e] == p); }
  const int tg = __popcll(bgt[0]) + __popcll(bgt[1]) + __popcll(bgt[2]) + __popcll(bgt[3]);
  const int need = K - tg;
  float* wV = ws + WV_OFF + (size_t)gch * K;
  int*   wI = (int*)(ws + WI_OFF) + (size_t)gch * K;
  int gpre = 0, epre = 0;
#pragma unroll
  for (int e = 0; e < 4; ++e) {
    const int myi = (c << 8) + e * 64 + lane;     // row-local index
    if (u[e] > p) {
      const int r = gpre + mbcnt64(bgt[e]);
      wV[r] = x[e]; wI[r] = myi;
    } else if (u[e] == p) {
      const int r = epre + mbcnt64(beq[e]);
      if (r < need) { wV[tg + r] = x[e]; wI[tg + r] = myi; }
    }
    gpre += __popcll(bgt[e]); epre += __popcll(beq[e]);
  }

  if (lane == 0) {
    (ws + WS_OFF)[gch] = s;
    (ws + WM_OFF)[gch] = mc;
  }
}

// ---------------- Kernel M: per-row merge -> constants + st one-hot scatter ----------------
// 64 blocks x 256 threads. Wave-level radix-select -> 64 survivors -> wave-0
// radix-select -> exact rank-sort of final 16 -> c_k, idx, m0; scatter 16 ones.
__global__ __launch_bounds__(256)
void gtk_merge(float* __restrict__ ws, float* __restrict__ st) {
  const int b = blockIdx.x;
  const int tid = threadIdx.x, wave = tid >> 6, lane = tid & 63;

  __shared__ float lv[64];
  __shared__ int   li[64];
  __shared__ float tv[K];
  __shared__ int   ti[K];
  __shared__ float sv16[K];
  __shared__ int   si16[K];

  const float* wV = ws + WV_OFF + (size_t)b * (NCH * K);
  const int*   wI = (const int*)(ws + WI_OFF) + (size_t)b * (NCH * K);

  float xv[4]; unsigned xu[4]; int xi[4];
#pragma unroll
  for (int e = 0; e < 4; ++e) {
    const int q = wave * 256 + e * 64 + lane;
    xv[e] = wV[q]; xi[e] = wI[q]; xu[e] = ordu(xv[e]);
  }

  unsigned p = 0;
#pragma unroll
  for (int bit = 31; bit >= 0; --bit) {
    const unsigned test = p | (1u << bit);
    int cnt = 0;
#pragma unroll
    for (int e = 0; e < 4; ++e) cnt += __popcll(__ballot(xu[e] >= test));
    if (cnt >= K) p = test;
  }
  unsigned long long bgt[4], beq[4];
#pragma unroll
  for (int e = 0; e < 4; ++e) { bgt[e] = __ballot(xu[e] > p); beq[e] = __ballot(xu[e] == p); }
  const int tg = __popcll(bgt[0]) + __popcll(bgt[1]) + __popcll(bgt[2]) + __popcll(bgt[3]);
  const int need = K - tg;
  int gpre = 0, epre = 0;
#pragma unroll
  for (int e = 0; e < 4; ++e) {
    if (xu[e] > p) {
      const int r = gpre + mbcnt64(bgt[e]);
      lv[wave * K + r] = xv[e]; li[wave * K + r] = xi[e];
    } else if (xu[e] == p) {
      const int r = epre + mbcnt64(beq[e]);
      if (r < need) { lv[wave * K + tg + r] = xv[e]; li[wave * K + tg + r] = xi[e]; }
    }
    gpre += __popcll(bgt[e]); epre += __popcll(beq[e]);
  }
  __syncthreads();

  if (wave == 0) {
    const float v = lv[lane]; const int i = li[lane];
    const unsigned uu = ordu(v);
    unsigned p2 = 0;
#pragma unroll
    for (int bit = 31; bit >= 0; --bit) {
      const unsigned test = p2 | (1u << bit);
      if (__popcll(__ballot(uu >= test)) >= K) p2 = test;
    }
    const unsigned long long g = __ballot(uu > p2);
    const unsigned long long q = __ballot(uu == p2);
    const int tg2 = __popcll(g), nd2 = K - tg2;
    if (uu > p2) {
      const int r = mbcnt64(g);
      tv[r] = v; ti[r] = i;
    } else if (uu == p2) {
      const int r = mbcnt64(q);
      if (r < nd2) { tv[tg2 + r] = v; ti[tg2 + r] = i; }
    }
    // exact order: rank by (value desc, original index asc)
    if (lane < K) {
      const float mv = tv[lane]; const int mi = ti[lane];
      int rk = 0;
#pragma unroll
      for (int j = 0; j < K; ++j) {
        const float ov = tv[j]; const int oi = ti[j];
        rk += (ov > mv || (ov == mv && oi < mi)) ? 1 : 0;
      }
      sv16[rk] = mv; si16[rk] = mi;
    }
    const float m0 = sv16[0];

    // A_all from chunk sums (NCH == 64 == wave width)
    const float S   = (ws + WS_OFF)[b * NCH + lane];
    const float mcc = (ws + WM_OFF)[b * NCH + lane];
    float a = S * __expf((mcc - m0) * 1.5f);
#pragma unroll
    for (int off = 32; off; off >>= 1) a += __shfl_xor(a, off);

    if (lane == 0) {
      float* wrow = ws + WC_OFF + (size_t)b * 48;
      float D = a;                                  // D_k = A_all - sum_{j<k} e_j
#pragma unroll
      for (int j = 0; j < K; ++j) {
        wrow[j] = 1.0f / D;
        D -= __expf((sv16[j] - m0) * 1.5f);
      }
      int* wi = (int*)(wrow + K);
#pragma unroll
      for (int j = 0; j < K; ++j) wi[j] = si16[j];
      wrow[32] = m0;
    }

    // scatter the one-hot 1s into st (P already zero-filled it)
    if (lane < K) {
      st[(size_t)lane * (size_t)(B * N) + (size_t)b * N + si16[lane]] = 1.0f;
    }
  }
}

// ---------------- Kernel S: softs, plane-contiguous linear walks ----------------
// 2048 blocks x 256 threads. Block = one 8192-elem (32 KB) contiguous run of ONE
// softs plane; plain float4 stores in an 8-iteration linear walk (fillBuffer-like).
// XCD swizzle: bid&7 = XCD; the 16 k-planes of a segment run on one XCD so the
// 64 KB input segment stays L2-hot. Selected-position zeroing is a post-loop
// same-thread fix-up (store order within a thread is program order).
__global__ __launch_bounds__(256)
void gtk_soft(const float* __restrict__ logits, const float* __restrict__ gumbel,
              const float* __restrict__ ws, float* __restrict__ softs) {
  const int bid = blockIdx.x, tid = threadIdx.x;
  const int xcd = bid & 7;
  const int j   = bid >> 3;
  const int k   = j & 15;
  const int s8  = j >> 4;               // [0,16)
  const int seg = s8 * 8 + xcd;         // [0,128)
  const int b   = seg >> 1;
  const int n0  = (seg & 1) << 13;      // 8192-elem half-row
  const size_t base = (size_t)b * N + n0;

  __shared__ float sck, sm0;
  __shared__ int   sidx[K];
  const float* wrow = ws + WC_OFF + (size_t)b * 48;
  if (tid < K) sidx[tid] = ((const int*)(wrow + K))[tid];
  if (tid == 0) { sck = wrow[k]; sm0 = wrow[32]; }
  __syncthreads();
  const float ck = sck, m0 = sm0;

  const float* lg = logits + base;
  const float* gm = gumbel + base;
  float* dst = softs + (size_t)k * (size_t)(B * N) + base;

#pragma unroll
  for (int i = 0; i < 8; ++i) {
    const int off = i * 1024 + (tid << 2);
    const f4 lv = *(const f4*)(lg + off);
    const f4 gv = *(const f4*)(gm + off);
    f4 s;
#pragma unroll
    for (int e = 0; e < 4; ++e)
      s[e] = __expf((lv[e] + gv[e] - m0) * 1.5f) * ck;
    *(f4*)(dst + off) = s;
  }

  // fix-up: zero the (at most k) positions selected before step k that fall in
  // my elements; same thread that wrote the f4 overwrites -> ordered.
#pragma unroll
  for (int jj = 0; jj < K; ++jj) {
    const int d = sidx[jj] - n0;
    if ((jj < k) && ((unsigned)d < 8192u) && (((d >> 2) & 255) == tid))
      dst[d] = 0.f;
  }
}

extern "C" void kernel_launch(void* const* d_in, const int* in_sizes, int n_in,
                              void* d_out, int out_size, void* d_ws, size_t ws_size,
                              hipStream_t stream) {
  const float* logits = (const float*)d_in[0];
  const float* gumbel = (const float*)d_in[1];
  float* st    = (float*)d_out;                      // [K,B,N]
  float* softs = st + (size_t)K * B * N;             // [K,B,N]
  float* ws    = (float*)d_ws;

  gtk_partial<<<(B * NCH) / 4, 256, 0, stream>>>(logits, gumbel, ws, st);
  gtk_merge<<<B, 256, 0, stream>>>(ws, st);
  gtk_soft<<<2048, 256, 0, stream>>>(logits, gumbel, ws, softs);
}

// Round 9
// 41.635 us; speedup vs baseline: 1.7172x; 1.0389x over previous
//
#include <hip/hip_runtime.h>
#include <math.h>

#define B 64
#define N 16384
#define K 16
#define CHUNK 256                 // elements per wave-chunk
#define NCH   (N / CHUNK)         // 64 chunks per row
// ws float layout:
//   wV [B][NCH][K]  candidate values  @ 0       (65536 floats)
//   wI [B][NCH][K]  candidate indices @ 65536   (65536 ints)
//   wS [B][NCH]     chunk exp sums    @ 131072  (4096)
//   wM [B][NCH]     chunk max         @ 135168  (4096)
//   wC [B][48]      row consts        @ 139264  (c[16], idx[16] int, m0@32)
//   wE [B*N] bf16   E-cache           @ 143360  (1M ushorts = 2 MB)
#define WV_OFF 0
#define WI_OFF 65536
#define WS_OFF 131072
#define WM_OFF 135168
#define WC_OFF 139264
#define WE_OFF 143360

typedef float f4 __attribute__((ext_vector_type(4)));
typedef unsigned short u16x8 __attribute__((ext_vector_type(8)));

// monotone map fp32 -> uint32 (no NaNs in data)
__device__ __forceinline__ unsigned ordu(float x) {
  unsigned i = __float_as_uint(x);
  return (i & 0x80000000u) ? ~i : (i | 0x80000000u);
}
__device__ __forceinline__ int mbcnt64(unsigned long long m) {
  return __builtin_amdgcn_mbcnt_hi((unsigned)(m >> 32),
         __builtin_amdgcn_mbcnt_lo((unsigned)m, 0u));
}
// f32 -> bf16 RTNE (inputs are finite, in [0,1])
__device__ __forceinline__ unsigned short f2bf(float f) {
  unsigned b = __float_as_uint(f);
  b += 0x7FFFu + ((b >> 16) & 1u);
  return (unsigned short)(b >> 16);
}
__device__ __forceinline__ float bf2f(unsigned short v) {
  return __uint_as_float(((unsigned)v) << 16);
}

// ---------------- Kernel P: per-chunk top-16 + exp sum + E-cache + st ZERO-FILL ----------------
// 1024 blocks x 256 threads; wave = one 256-elem chunk. Zero-fills a contiguous
// 64 KB region of st per block; persists E = exp((x-mc)*1.5) as bf16 to ws.
__global__ __launch_bounds__(256)
void gtk_partial(const float* __restrict__ logits, const float* __restrict__ gumbel,
                 float* __restrict__ ws, float* __restrict__ st) {
  const int tid  = threadIdx.x;
  const int wave = tid >> 6, lane = tid & 63;
  const int gch  = blockIdx.x * 4 + wave;        // global chunk id (b*NCH + c)
  const int c    = gch & (NCH - 1);
  const size_t base = (size_t)gch * CHUNK;

  // slot-major layout: element e of lane = base + e*64 + lane (slot order == index order)
  float x[4]; unsigned u[4];
#pragma unroll
  for (int e = 0; e < 4; ++e) {
    const int o = e * 64 + lane;
    x[e] = logits[base + o] + gumbel[base + o];
    u[e] = ordu(x[e]);
  }

  // ---- st zero-fill: block owns st[blk*16384 .. +16384) ----
  {
    float* zst = st + ((size_t)blockIdx.x << 14);
    const f4 z = {0.f, 0.f, 0.f, 0.f};
#pragma unroll
    for (int i = 0; i < 16; ++i)
      *(f4*)(zst + i * 1024 + (tid << 2)) = z;
  }

  // chunk max (butterfly)
  float mc = fmaxf(fmaxf(x[0], x[1]), fmaxf(x[2], x[3]));
#pragma unroll
  for (int off = 32; off; off >>= 1) mc = fmaxf(mc, __shfl_xor(mc, off));

  // E = exp((x-mc)*1.5): feed the chunk sum AND the bf16 E-cache
  unsigned short* wE = (unsigned short*)(ws + WE_OFF);
  float s = 0.f;
#pragma unroll
  for (int e = 0; e < 4; ++e) {
    const float Ee = __expf((x[e] - mc) * 1.5f);
    s += Ee;
    wE[base + e * 64 + lane] = f2bf(Ee);
  }
#pragma unroll
  for (int off = 32; off; off >>= 1) s += __shfl_xor(s, off);

  // radix bit-search: p = 16th largest orderable value in chunk
  unsigned p = 0;
#pragma unroll
  for (int bit = 31; bit >= 0; --bit) {
    const unsigned test = p | (1u << bit);
    int cnt = 0;
#pragma unroll
    for (int e = 0; e < 4; ++e) cnt += __popcll(__ballot(u[e] >= test));
    if (cnt >= K) p = test;
  }

  // extract top-16 set via ballot-prefix ranks (ties: smallest index first)
  unsigned long long bgt[4], beq[4];
#pragma unroll
  for (int e = 0; e < 4; ++e) { bgt[e] = __ballot(u[e] > p); beq[e] = __ballot(u[e] == p); }
  const int tg = __popcll(bgt[0]) + __popcll(bgt[1]) + __popcll(bgt[2]) + __popcll(bgt[3]);
  const int need = K - tg;
  float* wV = ws + WV_OFF + (size_t)gch * K;
  int*   wI = (int*)(ws + WI_OFF) + (size_t)gch * K;
  int gpre = 0, epre = 0;
#pragma unroll
  for (int e = 0; e < 4; ++e) {
    const int myi = (c << 8) + e * 64 + lane;     // row-local index
    if (u[e] > p) {
      const int r = gpre + mbcnt64(bgt[e]);
      wV[r] = x[e]; wI[r] = myi;
    } else if (u[e] == p) {
      const int r = epre + mbcnt64(beq[e]);
      if (r < need) { wV[tg + r] = x[e]; wI[tg + r] = myi; }
    }
    gpre += __popcll(bgt[e]); epre += __popcll(beq[e]);
  }

  if (lane == 0) {
    (ws + WS_OFF)[gch] = s;
    (ws + WM_OFF)[gch] = mc;
  }
}

// ---------------- Kernel M: per-row merge -> constants + st one-hot scatter ----------------
// 64 blocks x 256 threads. Wave-level radix-select -> 64 survivors -> wave-0
// radix-select -> exact rank-sort of final 16 -> c_k, idx, m0; scatter 16 ones.
__global__ __launch_bounds__(256)
void gtk_merge(float* __restrict__ ws, float* __restrict__ st) {
  const int b = blockIdx.x;
  const int tid = threadIdx.x, wave = tid >> 6, lane = tid & 63;

  __shared__ float lv[64];
  __shared__ int   li[64];
  __shared__ float tv[K];
  __shared__ int   ti[K];
  __shared__ float sv16[K];
  __shared__ int   si16[K];

  const float* wV = ws + WV_OFF + (size_t)b * (NCH * K);
  const int*   wI = (const int*)(ws + WI_OFF) + (size_t)b * (NCH * K);

  float xv[4]; unsigned xu[4]; int xi[4];
#pragma unroll
  for (int e = 0; e < 4; ++e) {
    const int q = wave * 256 + e * 64 + lane;
    xv[e] = wV[q]; xi[e] = wI[q]; xu[e] = ordu(xv[e]);
  }

  unsigned p = 0;
#pragma unroll
  for (int bit = 31; bit >= 0; --bit) {
    const unsigned test = p | (1u << bit);
    int cnt = 0;
#pragma unroll
    for (int e = 0; e < 4; ++e) cnt += __popcll(__ballot(xu[e] >= test));
    if (cnt >= K) p = test;
  }
  unsigned long long bgt[4], beq[4];
#pragma unroll
  for (int e = 0; e < 4; ++e) { bgt[e] = __ballot(xu[e] > p); beq[e] = __ballot(xu[e] == p); }
  const int tg = __popcll(bgt[0]) + __popcll(bgt[1]) + __popcll(bgt[2]) + __popcll(bgt[3]);
  const int need = K - tg;
  int gpre = 0, epre = 0;
#pragma unroll
  for (int e = 0; e < 4; ++e) {
    if (xu[e] > p) {
      const int r = gpre + mbcnt64(bgt[e]);
      lv[wave * K + r] = xv[e]; li[wave * K + r] = xi[e];
    } else if (xu[e] == p) {
      const int r = epre + mbcnt64(beq[e]);
      if (r < need) { lv[wave * K + tg + r] = xv[e]; li[wave * K + tg + r] = xi[e]; }
    }
    gpre += __popcll(bgt[e]); epre += __popcll(beq[e]);
  }
  __syncthreads();

  if (wave == 0) {
    const float v = lv[lane]; const int i = li[lane];
    const unsigned uu = ordu(v);
    unsigned p2 = 0;
#pragma unroll
    for (int bit = 31; bit >= 0; --bit) {
      const unsigned test = p2 | (1u << bit);
      if (__popcll(__ballot(uu >= test)) >= K) p2 = test;
    }
    const unsigned long long g = __ballot(uu > p2);
    const unsigned long long q = __ballot(uu == p2);
    const int tg2 = __popcll(g), nd2 = K - tg2;
    if (uu > p2) {
      const int r = mbcnt64(g);
      tv[r] = v; ti[r] = i;
    } else if (uu == p2) {
      const int r = mbcnt64(q);
      if (r < nd2) { tv[tg2 + r] = v; ti[tg2 + r] = i; }
    }
    // exact order: rank by (value desc, original index asc)
    if (lane < K) {
      const float mv = tv[lane]; const int mi = ti[lane];
      int rk = 0;
#pragma unroll
      for (int j = 0; j < K; ++j) {
        const float ov = tv[j]; const int oi = ti[j];
        rk += (ov > mv || (ov == mv && oi < mi)) ? 1 : 0;
      }
      sv16[rk] = mv; si16[rk] = mi;
    }
    const float m0 = sv16[0];

    // A_all from chunk sums (NCH == 64 == wave width)
    const float S   = (ws + WS_OFF)[b * NCH + lane];
    const float mcc = (ws + WM_OFF)[b * NCH + lane];
    float a = S * __expf((mcc - m0) * 1.5f);
#pragma unroll
    for (int off = 32; off; off >>= 1) a += __shfl_xor(a, off);

    if (lane == 0) {
      float* wrow = ws + WC_OFF + (size_t)b * 48;
      float D = a;                                  // D_k = A_all - sum_{j<k} e_j
#pragma unroll
      for (int j = 0; j < K; ++j) {
        wrow[j] = 1.0f / D;
        D -= __expf((sv16[j] - m0) * 1.5f);
      }
      int* wi = (int*)(wrow + K);
#pragma unroll
      for (int j = 0; j < K; ++j) wi[j] = si16[j];
      wrow[32] = m0;
    }

    // scatter the one-hot 1s into st (P already zero-filled it)
    if (lane < K) {
      st[(size_t)lane * (size_t)(B * N) + (size_t)b * N + si16[lane]] = 1.0f;
    }
  }
}

// ---------------- Kernel S: softs from the 2.1 MB bf16 E-cache ----------------
// 2048 blocks x 256 threads. Block = one 8192-elem (32 KB) contiguous run of ONE
// softs plane; reads 16 KB of E (cache-resident by size), rescales by the
// per-chunk factor exp((mc-m0)*1.5)*c_k, plain float4 store walk. Selected-
// position zeroing is a post-loop same-thread fix-up.
__global__ __launch_bounds__(256)
void gtk_soft(const float* __restrict__ ws, float* __restrict__ softs) {
  const int bid = blockIdx.x, tid = threadIdx.x;
  const int xcd = bid & 7;
  const int j   = bid >> 3;
  const int k   = j & 15;
  const int s8  = j >> 4;               // [0,16)
  const int seg = s8 * 8 + xcd;         // [0,128)
  const int b   = seg >> 1;
  const int n0  = (seg & 1) << 13;      // 8192-elem half-row
  const size_t base = (size_t)b * N + n0;

  __shared__ float ssc[32];             // per-local-chunk scale = exp((mc-m0)*1.5)*ck
  __shared__ int   sidx[K];
  const float* wrow = ws + WC_OFF + (size_t)b * 48;
  if (tid < K) sidx[tid] = ((const int*)(wrow + K))[tid];
  if (tid < 32) {
    const float m0  = wrow[32];
    const float ck  = wrow[k];
    const float mcc = (ws + WM_OFF)[b * NCH + (n0 >> 8) + tid];
    ssc[tid] = __expf((mcc - m0) * 1.5f) * ck;
  }
  __syncthreads();

  const unsigned short* Eb = (const unsigned short*)(ws + WE_OFF) + base;
  float* dst = softs + (size_t)k * (size_t)(B * N) + base;

#pragma unroll
  for (int i = 0; i < 4; ++i) {
    const int off = i * 2048 + (tid << 3);          // 8 elems/thread/iter
    const u16x8 ev = *(const u16x8*)(Eb + off);
    const float sc = ssc[i * 8 + (tid >> 5)];       // 8 consecutive elems: one chunk
    f4 s0, s1;
#pragma unroll
    for (int e = 0; e < 4; ++e) {
      s0[e] = bf2f(ev[e])     * sc;
      s1[e] = bf2f(ev[4 + e]) * sc;
    }
    *(f4*)(dst + off)     = s0;
    *(f4*)(dst + off + 4) = s1;
  }

  // fix-up: zero positions selected before step k; done by the SAME thread that
  // stored them (program order guarantees the zero lands last).
#pragma unroll
  for (int jj = 0; jj < K; ++jj) {
    const int d = sidx[jj] - n0;
    if ((jj < k) && ((unsigned)d < 8192u) && (((d & 2047) >> 3) == tid))
      dst[d] = 0.f;
  }
}

extern "C" void kernel_launch(void* const* d_in, const int* in_sizes, int n_in,
                              void* d_out, int out_size, void* d_ws, size_t ws_size,
                              hipStream_t stream) {
  const float* logits = (const float*)d_in[0];
  const float* gumbel = (const float*)d_in[1];
  float* st    = (float*)d_out;                      // [K,B,N]
  float* softs = st + (size_t)K * B * N;             // [K,B,N]
  float* ws    = (float*)d_ws;

  gtk_partial<<<(B * NCH) / 4, 256, 0, stream>>>(logits, gumbel, ws, st);
  gtk_merge<<<B, 256, 0, stream>>>(ws, st);
  gtk_soft<<<2048, 256, 0, stream>>>(ws, softs);
}